// Round 3
// baseline (454.031 us; speedup 1.0000x reference)
//
#include <hip/hip_runtime.h>
#include <math.h>
#include <string.h>

#define HH 2048
#define WW 2048
#define TROWS 8
#define NYB (HH / TROWS)   // 256 row-blocks (power of 2)

struct Wts { float w[17][5]; };

// angle index a: 0 -> -10deg, 1 -> 0deg, 2 -> +10deg
__host__ __device__ constexpr int js_fn(int a, int i) {
  return (a == 1) ? 2
       : (a == 2) ? ((i < 3) ? 0 : (i < 9) ? 1 : (i < 14) ? 2 : 3)
                  : ((i < 3) ? 3 : (i < 8) ? 2 : (i < 14) ? 1 : 0);
}
__host__ __device__ constexpr int nt_fn(int a, int i) {
  return (a == 1) ? 1 : (i == 8) ? 3 : 2;
}

__device__ __forceinline__ float fastrcp(float x) {
#if __has_builtin(__builtin_amdgcn_rcpf)
  return __builtin_amdgcn_rcpf(x);
#else
  return 1.0f / x;
#endif
}

// Difference-space pass:
//  MODE 0: P0=X, P1=Y. win = Y-X.   Out = cen - acc/N   (= D1)
//  MODE 1: P0=D.       win = D.     Out = cen - acc/N   (= D2)
//  MODE 2: P0=D, P1=Y. win = D.     Out = Ycen - cen + acc/N (= X3)
template <int ANGLE, int DENSE, int MODE, bool SAFEY>
__device__ __forceinline__ void do_rows(const float* __restrict__ A,
                                        const float* __restrict__ B,
                                        int x0, int y0, bool safex,
                                        float acc[TROWS][4], float cen[TROWS][4],
                                        const Wts& wts)
{
  constexpr bool WIN8 = (DENSE || ANGLE != 1);
  constexpr int  NW   = WIN8 ? 8 : 4;
  constexpr int  CO   = WIN8 ? 2 : 0;

#pragma unroll
  for (int rr = 0; rr < TROWS + 16; ++rr) {
    const int r = y0 - 8 + rr;              // uniform per block
    if (SAFEY || (r >= 0 && r < HH)) {
      const float* ar = A + (size_t)r * WW;
      const float* br = (MODE == 0) ? (B + (size_t)r * WW) : nullptr;
      float win[NW];
      if (WIN8) {
        if (safex) {
          const float2 a0 = *(const float2*)(ar + x0 - 2);
          const float4 a1 = *(const float4*)(ar + x0);
          const float2 a2 = *(const float2*)(ar + x0 + 4);
          if (MODE == 0) {
            const float2 b0 = *(const float2*)(br + x0 - 2);
            const float4 b1 = *(const float4*)(br + x0);
            const float2 b2 = *(const float2*)(br + x0 + 4);
            win[0] = b0.x - a0.x;  win[1] = b0.y - a0.y;
            win[2] = b1.x - a1.x;  win[3] = b1.y - a1.y;
            win[4] = b1.z - a1.z;  win[5] = b1.w - a1.w;
            win[6] = b2.x - a2.x;  win[7] = b2.y - a2.y;
          } else {
            win[0] = a0.x;  win[1] = a0.y;
            win[2] = a1.x;  win[3] = a1.y;
            win[4] = a1.z;  win[5] = a1.w;
            win[6] = a2.x;  win[7] = a2.y;
          }
        } else {
#pragma unroll
          for (int m = 0; m < 8; ++m) {
            const int xc = x0 - 2 + m;
            const bool v = (xc >= 0 && xc < WW);
            if (MODE == 0) win[m] = v ? (br[xc] - ar[xc]) : 0.0f;
            else           win[m] = v ? ar[xc] : 0.0f;
          }
        }
      } else {
        const float4 a1 = *(const float4*)(ar + x0);
        if (MODE == 0) {
          const float4 b1 = *(const float4*)(br + x0);
          win[0] = b1.x - a1.x;  win[1] = b1.y - a1.y;
          win[2] = b1.z - a1.z;  win[3] = b1.w - a1.w;
        } else {
          win[0] = a1.x;  win[1] = a1.y;  win[2] = a1.z;  win[3] = a1.w;
        }
      }
#pragma unroll
      for (int t = 0; t < TROWS; ++t) {
        const int i = rr - t;               // compile-time after unrolling
        if (i >= 0 && i <= 16) {
          if (i == 8) {
#pragma unroll
            for (int c = 0; c < 4; ++c) cen[t][c] = win[CO + c];
          }
          const int js = DENSE ? 0 : js_fn(ANGLE, i);
          const int nt = DENSE ? 5 : nt_fn(ANGLE, i);
#pragma unroll
          for (int jj = 0; jj < nt; ++jj) {
            const float wv = wts.w[i][js + jj];   // kernarg -> SGPR
#pragma unroll
            for (int c = 0; c < 4; ++c)
              acc[t][c] = fmaf(wv, win[(WIN8 ? 0 : -2) + c + js + jj], acc[t][c]);
          }
        }
      }
    }
  }
}

template <int ANGLE, int DENSE, int MODE>
__global__ __launch_bounds__(256, 4)
void conv_iter(const float* __restrict__ P0, const float* __restrict__ P1,
               const float* __restrict__ Nrm, float* __restrict__ Out, Wts wts)
{
  // --- bijective XCD swizzle on a 1-D grid: each XCD owns a contiguous band
  // of row-blocks so halo re-reads hit its private L2. ---
  const int nwg = gridDim.x;
  const int bid = blockIdx.x;
  const int q = nwg >> 3, rrem = nwg & 7;
  const int xcd = bid & 7, idx = bid >> 3;
  const int wg = (xcd < rrem ? xcd * (q + 1) : rrem * (q + 1) + (xcd - rrem) * q) + idx;
  // wg = bx + 2*(by + NYB*bz), bx fastest (full-width rows stay in-XCD)
  const int bx  = wg & 1;
  const int tmw = wg >> 1;
  const int by  = tmw & (NYB - 1);
  const int bz  = tmw >> 8;                 // NYB == 256

  const int tid = threadIdx.x;
  const int x0  = bx * (256 * 4) + tid * 4;
  const int y0  = by * TROWS;
  const size_t img = (size_t)bz * ((size_t)HH * WW);
  const float* A = P0 + img;
  const float* B = (MODE == 1) ? nullptr : P1 + img;

  float acc[TROWS][4];
  float cen[TROWS][4];
#pragma unroll
  for (int t = 0; t < TROWS; ++t)
#pragma unroll
    for (int c = 0; c < 4; ++c) { acc[t][c] = 0.0f; cen[t][c] = 0.0f; }

  constexpr bool WIN8 = (DENSE || ANGLE != 1);
  const bool safex = !WIN8 || ((x0 >= 4) && (x0 + 8 <= WW));
  const bool safey = (y0 >= 8) && (y0 + TROWS + 8 <= HH);   // uniform

  if (safey) do_rows<ANGLE, DENSE, MODE, true >(A, B, x0, y0, safex, acc, cen, wts);
  else       do_rows<ANGLE, DENSE, MODE, false>(A, B, x0, y0, safex, acc, cen, wts);

  float* Ob = Out + img;
#pragma unroll
  for (int t = 0; t < TROWS; ++t) {
    const int yo = y0 + t;
    const float4 nv = *(const float4*)(Nrm + (size_t)yo * WW + x0);
    float4 o;
    if (MODE == 2) {
      const float4 yv = *(const float4*)(B + (size_t)yo * WW + x0);
      o.x = yv.x - cen[t][0] + acc[t][0] * fastrcp(nv.x);
      o.y = yv.y - cen[t][1] + acc[t][1] * fastrcp(nv.y);
      o.z = yv.z - cen[t][2] + acc[t][2] * fastrcp(nv.z);
      o.w = yv.w - cen[t][3] + acc[t][3] * fastrcp(nv.w);
    } else {
      o.x = cen[t][0] - acc[t][0] * fastrcp(nv.x);
      o.y = cen[t][1] - acc[t][1] * fastrcp(nv.y);
      o.z = cen[t][2] - acc[t][2] * fastrcp(nv.z);
      o.w = cen[t][3] - acc[t][3] * fastrcp(nv.w);
    }
    *(float4*)(Ob + (size_t)yo * WW + x0) = o;
  }
}

// ---------------- host-side replication of _build_kernels ----------------

static void rotate33(const double* src, double* dst, double ang_deg) {
  const int n = 33;
  const double t = ang_deg * 3.14159265358979323846 / 180.0;
  const double cs = cos(t), sn = sin(t);
  for (int y = 0; y < n; ++y) {
    for (int x = 0; x < n; ++x) {
      const double y0 = y - 16.0, x0 = x - 16.0;
      const double sy = cs * y0 + sn * x0 + 16.0;
      const double sx = -sn * y0 + cs * x0 + 16.0;
      const double fy = floor(sy), fx = floor(sx);
      const int y0i = (int)fy, x0i = (int)fx;
      const double wy = sy - fy, wx = sx - fx;
      double o = 0.0;
      for (int dy = 0; dy < 2; ++dy)
        for (int dx = 0; dx < 2; ++dx) {
          const int yy = y0i + dy, xx = x0i + dx;
          if (yy < 0 || yy >= n || xx < 0 || xx >= n) continue;
          const double wgt = (dy ? wy : 1.0 - wy) * (dx ? wx : 1.0 - wx);
          o += wgt * src[yy * n + xx];
        }
      dst[y * n + x] = o;
    }
  }
}

static void build_K(float K[3][17][5]) {
  const double angs[3] = {-10.0, 0.0, 10.0};
  double base[33 * 33], rot[33 * 33];
  for (int i = 0; i < 33 * 33; ++i) base[i] = 0.0;
  for (int y = 0; y < 33; ++y) base[y * 33 + 16] = 1.0;  // ry==0 path
  for (int a = 0; a < 3; ++a) {
    if (a == 1) memcpy(rot, base, sizeof(rot));          // angle % 360 == 0
    else        rotate33(base, rot, angs[a]);
    double k17[17][17];
    for (int y = 0; y < 17; ++y)
      for (int x = 0; x < 17; ++x) k17[y][x] = rot[(y + 8) * 33 + (x + 8)];
    int r = 0, c = 0;
    for (int y = 0; y < 17; ++y) { bool nz = false; for (int x = 0; x < 17; ++x) if (k17[y][x] != 0.0) nz = true; r += nz; }
    for (int x = 0; x < 17; ++x) { bool nz = false; for (int y = 0; y < 17; ++y) if (k17[y][x] != 0.0) nz = true; c += nz; }
    r = r / 2 * 2; c = c / 2 * 2;
    const int kh = r + 1, kw = c + 1;
    for (int y = 0; y < 17; ++y)
      for (int x = 0; x < 5; ++x) K[a][y][x] = 0.0f;
    if (kh <= 17 && kw <= 5) {
      const int oh = (17 - kh) / 2, ow = (5 - kw) / 2;
      for (int y = 0; y < kh; ++y)
        for (int x = 0; x < kw; ++x)
          K[a][oh + y][ow + x] = (float)k17[8 - r / 2 + y][8 - c / 2 + x];
    }
  }
}

// 0 = structured (constexpr jstart/ntaps hold), 1 = dense 5-tap fallback
static int pick_mode(int a, const float K[17][5]) {
  for (int i = 0; i < 17; ++i) {
    const int js = js_fn(a, i), nt = nt_fn(a, i);
    for (int j = 0; j < 5; ++j)
      if ((j < js || j >= js + nt) && K[i][j] != 0.0f) return 1;
  }
  return 0;
}

template <int A, int MODE>
static void launch_iter(int dense, const float* P0, const float* P1, const float* Nrm,
                        float* Out, const Wts& w, int B, hipStream_t s) {
  dim3 grid((WW / 1024) * NYB * B), block(256);
  if (dense == 0) conv_iter<A, 0, MODE><<<grid, block, 0, s>>>(P0, P1, Nrm, Out, w);
  else            conv_iter<A, 1, MODE><<<grid, block, 0, s>>>(P0, P1, Nrm, Out, w);
}

extern "C" void kernel_launch(void* const* d_in, const int* in_sizes, int n_in,
                              void* d_out, int out_size, void* d_ws, size_t ws_size,
                              hipStream_t stream) {
  const float* X  = (const float*)d_in[0];
  const float* Y  = (const float*)d_in[1];
  const float* Nn = (const float*)d_in[3];
  float* out = (float*)d_out;
  float* tmp = (float*)d_ws;   // needs B*H*W*4 = 33.6 MB of scratch
  const size_t HW = (size_t)HH * WW;
  const int B = in_sizes[0] / (int)HW;   // 2

  float K[3][17][5];
  build_K(K);
  Wts w[3];
  for (int a = 0; a < 3; ++a) memcpy(w[a].w, K[a], sizeof(w[a].w));
  const int m0 = pick_mode(0, K[0]);
  const int m1 = pick_mode(1, K[1]);
  const int m2 = pick_mode(2, K[2]);

  // D1 -> d_out, D2 -> d_ws, X3 -> d_out (never read+write same buffer in a pass)
  launch_iter<0, 0>(m0, X,   Y,       Nn,          out, w[0], B, stream);  // D1
  launch_iter<1, 1>(m1, out, nullptr, Nn + HW,     tmp, w[1], B, stream);  // D2
  launch_iter<2, 2>(m2, tmp, Y,       Nn + 2 * HW, out, w[2], B, stream);  // X3
}

// Round 4
// 312.727 us; speedup vs baseline: 1.4518x; 1.4518x over previous
//
#include <hip/hip_runtime.h>
#include <math.h>
#include <string.h>

#define HH 2048
#define WW 2048
#define TROWS 8
#define NYB (HH / TROWS)   // 256 row-blocks

struct Wts { float w[17][5]; };

// angle index a: 0 -> -10deg, 1 -> 0deg, 2 -> +10deg
__host__ __device__ constexpr int js_fn(int a, int i) {
  return (a == 1) ? 2
       : (a == 2) ? ((i < 3) ? 0 : (i < 9) ? 1 : (i < 14) ? 2 : 3)
                  : ((i < 3) ? 3 : (i < 8) ? 2 : (i < 14) ? 1 : 0);
}
__host__ __device__ constexpr int nt_fn(int a, int i) {
  return (a == 1) ? 1 : (i == 8) ? 3 : 2;
}

__device__ __forceinline__ float fastrcp(float x) {
#if __has_builtin(__builtin_amdgcn_rcpf)
  return __builtin_amdgcn_rcpf(x);
#else
  return 1.0f / x;
#endif
}

// Difference-space pass:
//  MODE 0: P0=X, P1=Y. win = Y-X.   Out = cen - acc/N        (= D1)
//  MODE 1: P0=D.       win = D.     Out = cen - acc/N        (= D2)
//  MODE 2: P0=D, P1=Y. win = D.     Out = Ycen - cen + acc/N (= X3)
// INTERIOR=true: no row bounds checks (by in [1, NYB-2]).
// All arrays strictly local to this body -> SROA keeps them in VGPRs.
template <int ANGLE, int DENSE, int MODE, bool INTERIOR>
__global__ __launch_bounds__(256, 4)
void conv_iter(const float* __restrict__ P0, const float* __restrict__ P1,
               const float* __restrict__ Nrm, float* __restrict__ Out, Wts wts)
{
  constexpr bool WIN8 = (DENSE || ANGLE != 1);
  constexpr int  NW   = WIN8 ? 8 : 4;
  constexpr int  CO   = WIN8 ? 2 : 0;

  int bx, by, bz;
  if (INTERIOR) {
    // bijective XCD swizzle: each XCD owns a contiguous band of row-blocks
    const int nwg = gridDim.x, bid = blockIdx.x;
    const int q = nwg >> 3, r8 = nwg & 7;
    const int xcd = bid & 7, idx = bid >> 3;
    const int wg = (xcd < r8 ? xcd * (q + 1) : r8 * (q + 1) + (xcd - r8) * q) + idx;
    bx = wg & 1;
    const int t = wg >> 1;
    by = 1 + t % (NYB - 2);
    bz = t / (NYB - 2);
  } else {
    bx = blockIdx.x; by = blockIdx.y ? NYB - 1 : 0; bz = blockIdx.z;
  }

  const int tid = threadIdx.x;
  const int x0  = bx * (256 * 4) + tid * 4;
  const int y0  = by * TROWS;
  const size_t img = (size_t)bz * ((size_t)HH * WW);
  const float* A = P0 + img;
  const float* B = (MODE == 1) ? nullptr : P1 + img;

  // branchless x-edge handling: clamp addresses, mask values
  const bool lok = (x0 >= 4);         // win[0..1] (cols x0-2, x0-1) valid
  const bool rok = (x0 + 8 <= WW);    // win[6..7] (cols x0+4, x0+5) valid
  const int  xl  = lok ? x0 - 2 : 0;        // 8B-aligned
  const int  xr  = rok ? x0 + 4 : WW - 2;   // 8B-aligned

  float acc[TROWS][4];
  float cen[TROWS][4];
#pragma unroll
  for (int t = 0; t < TROWS; ++t)
#pragma unroll
    for (int c = 0; c < 4; ++c) { acc[t][c] = 0.0f; cen[t][c] = 0.0f; }

#pragma unroll
  for (int rr = 0; rr < TROWS + 16; ++rr) {
    const int r = y0 - 8 + rr;              // uniform per block
    if (INTERIOR || (r >= 0 && r < HH)) {
      const float* ar = A + (size_t)r * WW;
      float win[NW];
      if (WIN8) {
        const float2 a0 = *(const float2*)(ar + xl);
        const float4 a1 = *(const float4*)(ar + x0);
        const float2 a2 = *(const float2*)(ar + xr);
        if (MODE == 0) {
          const float* br = B + (size_t)r * WW;
          const float2 b0 = *(const float2*)(br + xl);
          const float4 b1 = *(const float4*)(br + x0);
          const float2 b2 = *(const float2*)(br + xr);
          win[0] = lok ? (b0.x - a0.x) : 0.0f;
          win[1] = lok ? (b0.y - a0.y) : 0.0f;
          win[2] = b1.x - a1.x;  win[3] = b1.y - a1.y;
          win[4] = b1.z - a1.z;  win[5] = b1.w - a1.w;
          win[6] = rok ? (b2.x - a2.x) : 0.0f;
          win[7] = rok ? (b2.y - a2.y) : 0.0f;
        } else {
          win[0] = lok ? a0.x : 0.0f;
          win[1] = lok ? a0.y : 0.0f;
          win[2] = a1.x;  win[3] = a1.y;
          win[4] = a1.z;  win[5] = a1.w;
          win[6] = rok ? a2.x : 0.0f;
          win[7] = rok ? a2.y : 0.0f;
        }
      } else {
        const float4 a1 = *(const float4*)(ar + x0);
        if (MODE == 0) {
          const float* br = B + (size_t)r * WW;
          const float4 b1 = *(const float4*)(br + x0);
          win[0] = b1.x - a1.x;  win[1] = b1.y - a1.y;
          win[2] = b1.z - a1.z;  win[3] = b1.w - a1.w;
        } else {
          win[0] = a1.x;  win[1] = a1.y;  win[2] = a1.z;  win[3] = a1.w;
        }
      }
#pragma unroll
      for (int t = 0; t < TROWS; ++t) {
        const int i = rr - t;               // compile-time after unrolling
        if (i >= 0 && i <= 16) {
          if (i == 8) {
#pragma unroll
            for (int c = 0; c < 4; ++c) cen[t][c] = win[CO + c];
          }
          const int js = DENSE ? 0 : js_fn(ANGLE, i);
          const int nt = DENSE ? 5 : nt_fn(ANGLE, i);
#pragma unroll
          for (int jj = 0; jj < nt; ++jj) {
            const float wv = wts.w[i][js + jj];   // kernarg -> SGPR
#pragma unroll
            for (int c = 0; c < 4; ++c)
              acc[t][c] = fmaf(wv, win[(WIN8 ? 0 : -2) + c + js + jj], acc[t][c]);
          }
        }
      }
    }
  }

  float* Ob = Out + img;
#pragma unroll
  for (int t = 0; t < TROWS; ++t) {
    const int yo = y0 + t;
    const float4 nv = *(const float4*)(Nrm + (size_t)yo * WW + x0);
    float4 o;
    if (MODE == 2) {
      const float4 yv = *(const float4*)(B + (size_t)yo * WW + x0);
      o.x = yv.x - cen[t][0] + acc[t][0] * fastrcp(nv.x);
      o.y = yv.y - cen[t][1] + acc[t][1] * fastrcp(nv.y);
      o.z = yv.z - cen[t][2] + acc[t][2] * fastrcp(nv.z);
      o.w = yv.w - cen[t][3] + acc[t][3] * fastrcp(nv.w);
    } else {
      o.x = cen[t][0] - acc[t][0] * fastrcp(nv.x);
      o.y = cen[t][1] - acc[t][1] * fastrcp(nv.y);
      o.z = cen[t][2] - acc[t][2] * fastrcp(nv.z);
      o.w = cen[t][3] - acc[t][3] * fastrcp(nv.w);
    }
    *(float4*)(Ob + (size_t)yo * WW + x0) = o;
  }
}

// ---------------- host-side replication of _build_kernels ----------------

static void rotate33(const double* src, double* dst, double ang_deg) {
  const int n = 33;
  const double t = ang_deg * 3.14159265358979323846 / 180.0;
  const double cs = cos(t), sn = sin(t);
  for (int y = 0; y < n; ++y) {
    for (int x = 0; x < n; ++x) {
      const double y0 = y - 16.0, x0 = x - 16.0;
      const double sy = cs * y0 + sn * x0 + 16.0;
      const double sx = -sn * y0 + cs * x0 + 16.0;
      const double fy = floor(sy), fx = floor(sx);
      const int y0i = (int)fy, x0i = (int)fx;
      const double wy = sy - fy, wx = sx - fx;
      double o = 0.0;
      for (int dy = 0; dy < 2; ++dy)
        for (int dx = 0; dx < 2; ++dx) {
          const int yy = y0i + dy, xx = x0i + dx;
          if (yy < 0 || yy >= n || xx < 0 || xx >= n) continue;
          const double wgt = (dy ? wy : 1.0 - wy) * (dx ? wx : 1.0 - wx);
          o += wgt * src[yy * n + xx];
        }
      dst[y * n + x] = o;
    }
  }
}

static void build_K(float K[3][17][5]) {
  const double angs[3] = {-10.0, 0.0, 10.0};
  double base[33 * 33], rot[33 * 33];
  for (int i = 0; i < 33 * 33; ++i) base[i] = 0.0;
  for (int y = 0; y < 33; ++y) base[y * 33 + 16] = 1.0;  // ry==0 path
  for (int a = 0; a < 3; ++a) {
    if (a == 1) memcpy(rot, base, sizeof(rot));          // angle % 360 == 0
    else        rotate33(base, rot, angs[a]);
    double k17[17][17];
    for (int y = 0; y < 17; ++y)
      for (int x = 0; x < 17; ++x) k17[y][x] = rot[(y + 8) * 33 + (x + 8)];
    int r = 0, c = 0;
    for (int y = 0; y < 17; ++y) { bool nz = false; for (int x = 0; x < 17; ++x) if (k17[y][x] != 0.0) nz = true; r += nz; }
    for (int x = 0; x < 17; ++x) { bool nz = false; for (int y = 0; y < 17; ++y) if (k17[y][x] != 0.0) nz = true; c += nz; }
    r = r / 2 * 2; c = c / 2 * 2;
    const int kh = r + 1, kw = c + 1;
    for (int y = 0; y < 17; ++y)
      for (int x = 0; x < 5; ++x) K[a][y][x] = 0.0f;
    if (kh <= 17 && kw <= 5) {
      const int oh = (17 - kh) / 2, ow = (5 - kw) / 2;
      for (int y = 0; y < kh; ++y)
        for (int x = 0; x < kw; ++x)
          K[a][oh + y][ow + x] = (float)k17[8 - r / 2 + y][8 - c / 2 + x];
    }
  }
}

// 0 = structured (constexpr jstart/ntaps hold), 1 = dense 5-tap fallback
static int pick_mode(int a, const float K[17][5]) {
  for (int i = 0; i < 17; ++i) {
    const int js = js_fn(a, i), nt = nt_fn(a, i);
    for (int j = 0; j < 5; ++j)
      if ((j < js || j >= js + nt) && K[i][j] != 0.0f) return 1;
  }
  return 0;
}

template <int A, int MODE>
static void launch_iter(int dense, const float* P0, const float* P1, const float* Nrm,
                        float* Out, const Wts& w, int B, hipStream_t s) {
  dim3 gi((WW / 1024) * (NYB - 2) * B);       // interior: 1-D, XCD-swizzled
  dim3 gb(WW / 1024, 2, B);                   // boundary: by = 0 and NYB-1
  dim3 blk(256);
  if (dense == 0) {
    conv_iter<A, 0, MODE, true ><<<gi, blk, 0, s>>>(P0, P1, Nrm, Out, w);
    conv_iter<A, 0, MODE, false><<<gb, blk, 0, s>>>(P0, P1, Nrm, Out, w);
  } else {
    conv_iter<A, 1, MODE, true ><<<gi, blk, 0, s>>>(P0, P1, Nrm, Out, w);
    conv_iter<A, 1, MODE, false><<<gb, blk, 0, s>>>(P0, P1, Nrm, Out, w);
  }
}

extern "C" void kernel_launch(void* const* d_in, const int* in_sizes, int n_in,
                              void* d_out, int out_size, void* d_ws, size_t ws_size,
                              hipStream_t stream) {
  const float* X  = (const float*)d_in[0];
  const float* Y  = (const float*)d_in[1];
  const float* Nn = (const float*)d_in[3];
  float* out = (float*)d_out;
  float* tmp = (float*)d_ws;   // needs B*H*W*4 = 33.6 MB of scratch
  const size_t HW = (size_t)HH * WW;
  const int B = in_sizes[0] / (int)HW;   // 2

  float K[3][17][5];
  build_K(K);
  Wts w[3];
  for (int a = 0; a < 3; ++a) memcpy(w[a].w, K[a], sizeof(w[a].w));
  const int m0 = pick_mode(0, K[0]);
  const int m1 = pick_mode(1, K[1]);
  const int m2 = pick_mode(2, K[2]);

  // D1 -> d_out, D2 -> d_ws, X3 -> d_out (never read+write same buffer in a pass)
  launch_iter<0, 0>(m0, X,   Y,       Nn,          out, w[0], B, stream);  // D1
  launch_iter<1, 1>(m1, out, nullptr, Nn + HW,     tmp, w[1], B, stream);  // D2
  launch_iter<2, 2>(m2, tmp, Y,       Nn + 2 * HW, out, w[2], B, stream);  // X3
}

// Round 5
// 106.173 us; speedup vs baseline: 4.2763x; 2.9455x over previous
//
#include <hip/hip_runtime.h>
#include <math.h>
#include <string.h>

#define HH 2048
#define WW 2048
#define TS_COLS 256            // output tile cols
#define TS_ROWS 32             // output tile rows
#define L_ROWS  48             // staged rows = TS_ROWS + 16
#define L_COLS  272            // staged cols = TS_COLS + 16, float4-aligned
#define NBX (WW / TS_COLS)     // 8
#define NBY (HH / TS_ROWS)     // 64

struct Wts { float w[17][5]; };

// angle index a: 0 -> -10deg, 1 -> 0deg, 2 -> +10deg
__host__ __device__ constexpr int js_fn(int a, int i) {
  return (a == 1) ? 2
       : (a == 2) ? ((i < 3) ? 0 : (i < 9) ? 1 : (i < 14) ? 2 : 3)
                  : ((i < 3) ? 3 : (i < 8) ? 2 : (i < 14) ? 1 : 0);
}
__host__ __device__ constexpr int nt_fn(int a, int i) {
  return (a == 1) ? 1 : (i == 8) ? 3 : 2;
}

__device__ __forceinline__ float fastrcp(float x) {
#if __has_builtin(__builtin_amdgcn_rcpf)
  return __builtin_amdgcn_rcpf(x);
#else
  return 1.0f / x;
#endif
}

// Difference-space pass (LDS-staged):
//  MODE 0: P0=X, P1=Y. LDS = Y-X.  Out = cen - acc/N        (= D1)
//  MODE 1: P0=D.       LDS = D.    Out = cen - acc/N        (= D2)
//  MODE 2: P0=D, P1=Y. LDS = D.    Out = Ycen - cen + acc/N (= X3)
// Thread: 4 cols x 8 rows of the 256x32 tile. cen read from LDS (no regs).
template <int ANGLE, int DENSE, int MODE>
__global__ __launch_bounds__(256, 3)
void conv_iter(const float* __restrict__ P0, const float* __restrict__ P1,
               const float* __restrict__ Nrm, float* __restrict__ Out, Wts wts)
{
  constexpr bool WIN8 = (DENSE || ANGLE != 1);   // angle 0 = single-column kernel
  __shared__ float lds[L_ROWS][L_COLS];          // 52224 B -> 3 blocks/CU

  // Bijective XCD swizzle: gridDim.x = 512*B divisible by 8. Each XCD gets a
  // contiguous band of tiles (bx fastest, then by) -> vertical-halo L2 hits.
  const int bid = blockIdx.x;
  const int wg  = (bid & 7) * (gridDim.x >> 3) + (bid >> 3);
  const int bx  = wg & (NBX - 1);
  const int rem = wg >> 3;                       // NBX == 8
  const int by  = rem & (NBY - 1);
  const int bz  = rem >> 6;                      // NBY == 64

  const int tid = threadIdx.x;
  const int tc  = tid & 63;                      // column-group 0..63
  const int tg  = tid >> 6;                      // row-group 0..3
  const int x0  = bx * TS_COLS;
  const int y0  = by * TS_ROWS;
  const size_t img = (size_t)bz * ((size_t)HH * WW);
  const float* A  = P0 + img;
  const float* Bp = (MODE == 1) ? nullptr : P1 + img;

  // ---- stage 48 x 272 window of (Y-X) or D into LDS, zero-filled OOB ----
#pragma unroll
  for (int rs = 0; rs < 12; ++rs) {
    const int r  = rs * 4 + tg;
    const int gy = y0 - 8 + r;
    const bool rowok = (gy >= 0) && (gy < HH);
    const float* arow = A + (size_t)gy * WW;
    const float* brow = (MODE == 0) ? (Bp + (size_t)gy * WW) : nullptr;
#pragma unroll
    for (int step = 0; step < 2; ++step) {
      const int c4 = step ? (64 + tc) : tc;      // 68 float4 per row
      if (step == 0 || tc < 4) {
        const int gx = x0 - 8 + c4 * 4;
        float4 v = make_float4(0.f, 0.f, 0.f, 0.f);
        if (rowok) {
          if (gx >= 0 && gx + 4 <= WW) {
            if (MODE == 0) {
              const float4 xa = *(const float4*)(arow + gx);
              const float4 yb = *(const float4*)(brow + gx);
              v = make_float4(yb.x - xa.x, yb.y - xa.y, yb.z - xa.z, yb.w - xa.w);
            } else {
              v = *(const float4*)(arow + gx);
            }
          } else {
            float t0 = 0.f, t1 = 0.f, t2 = 0.f, t3 = 0.f;
            if (gx + 0 >= 0 && gx + 0 < WW) t0 = (MODE == 0) ? (brow[gx+0] - arow[gx+0]) : arow[gx+0];
            if (gx + 1 >= 0 && gx + 1 < WW) t1 = (MODE == 0) ? (brow[gx+1] - arow[gx+1]) : arow[gx+1];
            if (gx + 2 >= 0 && gx + 2 < WW) t2 = (MODE == 0) ? (brow[gx+2] - arow[gx+2]) : arow[gx+2];
            if (gx + 3 >= 0 && gx + 3 < WW) t3 = (MODE == 0) ? (brow[gx+3] - arow[gx+3]) : arow[gx+3];
            v = make_float4(t0, t1, t2, t3);
          }
        }
        *(float4*)(&lds[r][c4 * 4]) = v;
      }
    }
  }
  __syncthreads();

  // ---- convolution from LDS: diagonal reuse, acc only (32 floats live) ----
  float acc[8][4];
#pragma unroll
  for (int t = 0; t < 8; ++t)
#pragma unroll
    for (int c = 0; c < 4; ++c) acc[t][c] = 0.0f;

  const int lc = tc * 4;                          // output col within tile

#pragma unroll
  for (int rr = 0; rr < 24; ++rr) {
    const int lrow = tg * 8 + rr;
    float win[WIN8 ? 8 : 4];
    if (WIN8) {
      const float2 w0 = *(const float2*)(&lds[lrow][6 + lc]);
      const float4 w1 = *(const float4*)(&lds[lrow][8 + lc]);
      const float2 w2 = *(const float2*)(&lds[lrow][12 + lc]);
      win[0] = w0.x;  win[1] = w0.y;
      win[2] = w1.x;  win[3] = w1.y;  win[4] = w1.z;  win[5] = w1.w;
      win[6] = w2.x;  win[7] = w2.y;
    } else {
      const float4 w1 = *(const float4*)(&lds[lrow][8 + lc]);
      win[0] = w1.x;  win[1] = w1.y;  win[2] = w1.z;  win[3] = w1.w;
    }
#pragma unroll
    for (int t = 0; t < 8; ++t) {
      const int i = rr - t;                       // compile-time after unroll
      if (i >= 0 && i <= 16) {
        const int js = DENSE ? 0 : js_fn(ANGLE, i);
        const int nt = DENSE ? 5 : nt_fn(ANGLE, i);
#pragma unroll
        for (int jj = 0; jj < nt; ++jj) {
          const float wv = wts.w[i][js + jj];     // kernarg -> SGPR
#pragma unroll
          for (int c = 0; c < 4; ++c)
            acc[t][c] = fmaf(wv, win[(WIN8 ? 0 : -2) + c + js + jj], acc[t][c]);
        }
      }
    }
  }

  // ---- epilogue: cen from LDS, N (and Y for MODE 2) from global ----
  float* Ob = Out + img;
  const int gx = x0 + lc;
#pragma unroll
  for (int t = 0; t < 8; ++t) {
    const int yo = y0 + tg * 8 + t;
    const float4 nv = *(const float4*)(Nrm + (size_t)yo * WW + gx);
    const float4 cv = *(const float4*)(&lds[tg * 8 + t + 8][8 + lc]);
    float4 o;
    if (MODE == 2) {
      const float4 yv = *(const float4*)(Bp + (size_t)yo * WW + gx);
      o.x = yv.x - cv.x + acc[t][0] * fastrcp(nv.x);
      o.y = yv.y - cv.y + acc[t][1] * fastrcp(nv.y);
      o.z = yv.z - cv.z + acc[t][2] * fastrcp(nv.z);
      o.w = yv.w - cv.w + acc[t][3] * fastrcp(nv.w);
    } else {
      o.x = cv.x - acc[t][0] * fastrcp(nv.x);
      o.y = cv.y - acc[t][1] * fastrcp(nv.y);
      o.z = cv.z - acc[t][2] * fastrcp(nv.z);
      o.w = cv.w - acc[t][3] * fastrcp(nv.w);
    }
    *(float4*)(Ob + (size_t)yo * WW + gx) = o;
  }
}

// ---------------- host-side replication of _build_kernels ----------------

static void rotate33(const double* src, double* dst, double ang_deg) {
  const int n = 33;
  const double t = ang_deg * 3.14159265358979323846 / 180.0;
  const double cs = cos(t), sn = sin(t);
  for (int y = 0; y < n; ++y) {
    for (int x = 0; x < n; ++x) {
      const double y0 = y - 16.0, x0 = x - 16.0;
      const double sy = cs * y0 + sn * x0 + 16.0;
      const double sx = -sn * y0 + cs * x0 + 16.0;
      const double fy = floor(sy), fx = floor(sx);
      const int y0i = (int)fy, x0i = (int)fx;
      const double wy = sy - fy, wx = sx - fx;
      double o = 0.0;
      for (int dy = 0; dy < 2; ++dy)
        for (int dx = 0; dx < 2; ++dx) {
          const int yy = y0i + dy, xx = x0i + dx;
          if (yy < 0 || yy >= n || xx < 0 || xx >= n) continue;
          const double wgt = (dy ? wy : 1.0 - wy) * (dx ? wx : 1.0 - wx);
          o += wgt * src[yy * n + xx];
        }
      dst[y * n + x] = o;
    }
  }
}

static void build_K(float K[3][17][5]) {
  const double angs[3] = {-10.0, 0.0, 10.0};
  double base[33 * 33], rot[33 * 33];
  for (int i = 0; i < 33 * 33; ++i) base[i] = 0.0;
  for (int y = 0; y < 33; ++y) base[y * 33 + 16] = 1.0;  // ry==0 path
  for (int a = 0; a < 3; ++a) {
    if (a == 1) memcpy(rot, base, sizeof(rot));          // angle % 360 == 0
    else        rotate33(base, rot, angs[a]);
    double k17[17][17];
    for (int y = 0; y < 17; ++y)
      for (int x = 0; x < 17; ++x) k17[y][x] = rot[(y + 8) * 33 + (x + 8)];
    int r = 0, c = 0;
    for (int y = 0; y < 17; ++y) { bool nz = false; for (int x = 0; x < 17; ++x) if (k17[y][x] != 0.0) nz = true; r += nz; }
    for (int x = 0; x < 17; ++x) { bool nz = false; for (int y = 0; y < 17; ++y) if (k17[y][x] != 0.0) nz = true; c += nz; }
    r = r / 2 * 2; c = c / 2 * 2;
    const int kh = r + 1, kw = c + 1;
    for (int y = 0; y < 17; ++y)
      for (int x = 0; x < 5; ++x) K[a][y][x] = 0.0f;
    if (kh <= 17 && kw <= 5) {
      const int oh = (17 - kh) / 2, ow = (5 - kw) / 2;
      for (int y = 0; y < kh; ++y)
        for (int x = 0; x < kw; ++x)
          K[a][oh + y][ow + x] = (float)k17[8 - r / 2 + y][8 - c / 2 + x];
    }
  }
}

// 0 = structured (constexpr jstart/ntaps hold), 1 = dense 5-tap fallback
static int pick_mode(int a, const float K[17][5]) {
  for (int i = 0; i < 17; ++i) {
    const int js = js_fn(a, i), nt = nt_fn(a, i);
    for (int j = 0; j < 5; ++j)
      if ((j < js || j >= js + nt) && K[i][j] != 0.0f) return 1;
  }
  return 0;
}

template <int A, int MODE>
static void launch_iter(int dense, const float* P0, const float* P1, const float* Nrm,
                        float* Out, const Wts& w, int B, hipStream_t s) {
  dim3 grid(NBX * NBY * B), blk(256);
  if (dense == 0) conv_iter<A, 0, MODE><<<grid, blk, 0, s>>>(P0, P1, Nrm, Out, w);
  else            conv_iter<A, 1, MODE><<<grid, blk, 0, s>>>(P0, P1, Nrm, Out, w);
}

extern "C" void kernel_launch(void* const* d_in, const int* in_sizes, int n_in,
                              void* d_out, int out_size, void* d_ws, size_t ws_size,
                              hipStream_t stream) {
  const float* X  = (const float*)d_in[0];
  const float* Y  = (const float*)d_in[1];
  const float* Nn = (const float*)d_in[3];
  float* out = (float*)d_out;
  float* tmp = (float*)d_ws;   // needs B*H*W*4 = 33.6 MB of scratch
  const size_t HW = (size_t)HH * WW;
  const int B = in_sizes[0] / (int)HW;   // 2

  float K[3][17][5];
  build_K(K);
  Wts w[3];
  for (int a = 0; a < 3; ++a) memcpy(w[a].w, K[a], sizeof(w[a].w));
  const int m0 = pick_mode(0, K[0]);
  const int m1 = pick_mode(1, K[1]);
  const int m2 = pick_mode(2, K[2]);

  // D1 -> d_out, D2 -> d_ws, X3 -> d_out (never read+write same buffer in a pass)
  launch_iter<0, 0>(m0, X,   Y,       Nn,          out, w[0], B, stream);  // D1
  launch_iter<1, 1>(m1, out, nullptr, Nn + HW,     tmp, w[1], B, stream);  // D2
  launch_iter<2, 2>(m2, tmp, Y,       Nn + 2 * HW, out, w[2], B, stream);  // X3
}